// Round 1
// baseline (1163.469 us; speedup 1.0000x reference)
//
#include <hip/hip_runtime.h>
#include <math.h>

// Problem constants
#define B_      8
#define C_      512
#define L_      1024          // H*W = 32*32
#define NH_     8
#define D_      64            // head dim
#define INNER_  512
#define GROUPS_ 32
#define CPG_    16            // channels per group
#define BH_     (B_ * NH_)    // 64
#define EPS_    1e-5f

// ---------------------------------------------------------------------------
// GroupNorm: one block per (b, group). 16 ch x 1024 = 16384 elems.
// ---------------------------------------------------------------------------
__global__ void __launch_bounds__(256) gn_kernel(
    const float* __restrict__ x, const float* __restrict__ gamma,
    const float* __restrict__ beta, float* __restrict__ xn) {
  int bg = blockIdx.x;
  int b = bg / GROUPS_, g = bg % GROUPS_;
  const int n = CPG_ * L_;  // 16384
  const float* xp = x + ((size_t)b * C_ + (size_t)g * CPG_) * L_;
  float s = 0.f, ss = 0.f;
  for (int i = threadIdx.x; i < n; i += 256) {
    float v = xp[i];
    s += v; ss += v * v;
  }
  __shared__ float red0[256], red1[256];
  red0[threadIdx.x] = s; red1[threadIdx.x] = ss;
  __syncthreads();
  for (int off = 128; off > 0; off >>= 1) {
    if (threadIdx.x < off) {
      red0[threadIdx.x] += red0[threadIdx.x + off];
      red1[threadIdx.x] += red1[threadIdx.x + off];
    }
    __syncthreads();
  }
  float mean = red0[0] / (float)n;
  float var  = red1[0] / (float)n - mean * mean;
  float rstd = rsqrtf(var + EPS_);
  float* yp = xn + ((size_t)b * C_ + (size_t)g * CPG_) * L_;
  for (int i = threadIdx.x; i < n; i += 256) {
    int c = g * CPG_ + (i >> 10);  // i / L_
    yp[i] = (xp[i] - mean) * rstd * gamma[c] + beta[c];
  }
}

// ---------------------------------------------------------------------------
// 1x1 conv (channel-wise linear): Y[b,o,l] = sum_c W[o,c]*X[b,c,l] + bias[o]
// (+ optional residual). O = C = 512. Tile 64(o) x 64(l), K-step 16.
// grid: (L/64, O/64, B), block 256 (16x16, 4x4 accum each).
// ---------------------------------------------------------------------------
__global__ void __launch_bounds__(256) conv1x1_kernel(
    const float* __restrict__ W, const float* __restrict__ bias,
    const float* __restrict__ X, const float* __restrict__ R,
    float* __restrict__ Y, int addResid) {
  int ltile = blockIdx.x * 64, otile = blockIdx.y * 64, b = blockIdx.z;
  int tid = threadIdx.x;
  int tx = tid & 15, ty = tid >> 4;
  int lx = tid & 63, cx = tid >> 6;  // for X loads
  __shared__ float Ws[16][65];  // [c][o]
  __shared__ float Xs[16][65];  // [c][l]
  float acc[4][4] = {};
  const float* Xb = X + (size_t)b * C_ * L_;

  for (int c0 = 0; c0 < C_; c0 += 16) {
    // W tile: 64 o x 16 c. thread: c = tx, o = r*16 + ty
#pragma unroll
    for (int r = 0; r < 4; ++r) {
      int o = otile + r * 16 + ty;
      Ws[tx][r * 16 + ty] = W[(size_t)o * C_ + c0 + tx];
    }
    // X tile: 16 c x 64 l. thread: l = lx, c = r*4 + cx  (coalesced 64-wide)
#pragma unroll
    for (int r = 0; r < 4; ++r) {
      int cc = r * 4 + cx;
      Xs[cc][lx] = Xb[(size_t)(c0 + cc) * L_ + ltile + lx];
    }
    __syncthreads();
#pragma unroll
    for (int kk = 0; kk < 16; ++kk) {
      float av[4], bv[4];
#pragma unroll
      for (int i = 0; i < 4; ++i) av[i] = Ws[kk][ty * 4 + i];
#pragma unroll
      for (int j = 0; j < 4; ++j) bv[j] = Xs[kk][tx * 4 + j];
#pragma unroll
      for (int i = 0; i < 4; ++i)
#pragma unroll
        for (int j = 0; j < 4; ++j) acc[i][j] += av[i] * bv[j];
    }
    __syncthreads();
  }

#pragma unroll
  for (int i = 0; i < 4; ++i) {
    int o = otile + ty * 4 + i;
    float bia = bias[o];
#pragma unroll
    for (int j = 0; j < 4; ++j) {
      int l = ltile + tx * 4 + j;
      size_t idx = ((size_t)b * INNER_ + o) * L_ + l;
      float vv = acc[i][j] + bia;
      if (addResid) vv += R[idx];
      Y[idx] = vv;
    }
  }
}

// ---------------------------------------------------------------------------
// Scores: S[bh,t,s] = 0.125 * sum_d q[bh,d,t]*k[bh,d,s]   (raw attn_map out)
// grid: (L/64 s, L/64 t, BH), block 256. K-dim = 64, step 16.
// ---------------------------------------------------------------------------
__global__ void __launch_bounds__(256) scores_kernel(
    const float* __restrict__ q, const float* __restrict__ k,
    float* __restrict__ S) {
  int stile = blockIdx.x * 64, ttile = blockIdx.y * 64, bh = blockIdx.z;
  int tid = threadIdx.x;
  int tx = tid & 15, ty = tid >> 4;
  int lx = tid & 63, cx = tid >> 6;
  __shared__ float Qs[16][65];  // [d][t]
  __shared__ float Ks[16][65];  // [d][s]
  float acc[4][4] = {};
  const float* qb = q + (size_t)bh * D_ * L_;
  const float* kb = k + (size_t)bh * D_ * L_;

  for (int d0 = 0; d0 < D_; d0 += 16) {
#pragma unroll
    for (int r = 0; r < 4; ++r) {
      int dd = r * 4 + cx;
      Qs[dd][lx] = qb[(size_t)(d0 + dd) * L_ + ttile + lx];
      Ks[dd][lx] = kb[(size_t)(d0 + dd) * L_ + stile + lx];
    }
    __syncthreads();
#pragma unroll
    for (int kk = 0; kk < 16; ++kk) {
      float av[4], bv[4];
#pragma unroll
      for (int i = 0; i < 4; ++i) av[i] = Qs[kk][ty * 4 + i];  // t
#pragma unroll
      for (int j = 0; j < 4; ++j) bv[j] = Ks[kk][tx * 4 + j];  // s
#pragma unroll
      for (int i = 0; i < 4; ++i)
#pragma unroll
        for (int j = 0; j < 4; ++j) acc[i][j] += av[i] * bv[j];
    }
    __syncthreads();
  }

  float* Sb = S + (size_t)bh * L_ * L_;
#pragma unroll
  for (int i = 0; i < 4; ++i) {
    int t = ttile + ty * 4 + i;
#pragma unroll
    for (int j = 0; j < 4; ++j) {
      int s = stile + tx * 4 + j;
      Sb[(size_t)t * L_ + s] = acc[i][j] * 0.125f;
    }
  }
}

// ---------------------------------------------------------------------------
// Softmax row stats: per row (bh*L + t) compute max and 1/sum(exp(x-max)).
// One wave (64 lanes) per row, 4 rows per block.
// ---------------------------------------------------------------------------
__global__ void __launch_bounds__(256) softmax_stats_kernel(
    const float* __restrict__ S, float2* __restrict__ stats) {
  int row = blockIdx.x * 4 + (threadIdx.x >> 6);
  int lane = threadIdx.x & 63;
  const float* rp = S + (size_t)row * L_;
  float vals[16];
  float m = -INFINITY;
#pragma unroll
  for (int i = 0; i < 16; ++i) {
    vals[i] = rp[lane + i * 64];
    m = fmaxf(m, vals[i]);
  }
#pragma unroll
  for (int off = 32; off > 0; off >>= 1) m = fmaxf(m, __shfl_xor(m, off));
  float s = 0.f;
#pragma unroll
  for (int i = 0; i < 16; ++i) s += expf(vals[i] - m);
#pragma unroll
  for (int off = 32; off > 0; off >>= 1) s += __shfl_xor(s, off);
  if (lane == 0) stats[row] = make_float2(m, 1.0f / s);
}

// ---------------------------------------------------------------------------
// PV: a[bh,d,t] = sum_s softmax(S)[t,s] * v[bh,d,s], softmax applied on the
// fly from row stats. grid: (L/64 t, BH), block 256. K(s)-step 64.
// ---------------------------------------------------------------------------
__global__ void __launch_bounds__(256) pv_kernel(
    const float* __restrict__ S, const float2* __restrict__ stats,
    const float* __restrict__ v, float* __restrict__ a) {
  int ttile = blockIdx.x * 64, bh = blockIdx.y;
  int tid = threadIdx.x;
  int tx = tid & 15, ty = tid >> 4;
  int lx = tid & 63, cx = tid >> 6;
  __shared__ float Vs[64][65];  // [s][d]
  __shared__ float Ps[64][65];  // [s][t]
  float acc[4][4] = {};
  const float*  vb  = v + (size_t)bh * D_ * L_;
  const float*  Sb  = S + (size_t)bh * L_ * L_;
  const float2* stb = stats + (size_t)bh * L_;

  for (int s0 = 0; s0 < L_; s0 += 64) {
    // V tile: 64 s x 64 d. thread: s = lx, d = r*4 + cx (coalesced 64-wide)
#pragma unroll
    for (int r = 0; r < 16; ++r) {
      int d = r * 4 + cx;
      Vs[lx][d] = vb[(size_t)d * L_ + s0 + lx];
    }
    // P tile: softmaxed scores, [s][t]. thread: s = lx, t = r*4 + cx
#pragma unroll
    for (int r = 0; r < 16; ++r) {
      int t = r * 4 + cx;
      float2 st = stb[ttile + t];
      float val = Sb[(size_t)(ttile + t) * L_ + s0 + lx];
      Ps[lx][t] = expf(val - st.x) * st.y;
    }
    __syncthreads();
#pragma unroll
    for (int kk = 0; kk < 64; ++kk) {
      float av[4], bv[4];
#pragma unroll
      for (int i = 0; i < 4; ++i) av[i] = Vs[kk][ty * 4 + i];  // d
#pragma unroll
      for (int j = 0; j < 4; ++j) bv[j] = Ps[kk][tx * 4 + j];  // t
#pragma unroll
      for (int i = 0; i < 4; ++i)
#pragma unroll
        for (int j = 0; j < 4; ++j) acc[i][j] += av[i] * bv[j];
    }
    __syncthreads();
  }

  float* ab = a + (size_t)bh * D_ * L_;
#pragma unroll
  for (int i = 0; i < 4; ++i) {
    int d = ty * 4 + i;
#pragma unroll
    for (int j = 0; j < 4; ++j) {
      int t = ttile + tx * 4 + j;
      ab[(size_t)d * L_ + t] = acc[i][j];
    }
  }
}

// ---------------------------------------------------------------------------
extern "C" void kernel_launch(void* const* d_in, const int* in_sizes, int n_in,
                              void* d_out, int out_size, void* d_ws, size_t ws_size,
                              hipStream_t stream) {
  const float* x     = (const float*)d_in[0];
  // d_in[1] = c (unused by module)
  const float* gam   = (const float*)d_in[2];
  const float* bet   = (const float*)d_in[3];
  const float* Wq    = (const float*)d_in[4];
  const float* bq    = (const float*)d_in[5];
  const float* Wk    = (const float*)d_in[6];
  const float* bk    = (const float*)d_in[7];
  const float* Wv    = (const float*)d_in[8];
  const float* bv    = (const float*)d_in[9];
  const float* Wo    = (const float*)d_in[10];
  const float* bo    = (const float*)d_in[11];

  const size_t NELEM = (size_t)B_ * C_ * L_;  // 4194304
  float* out  = (float*)d_out;                // out: B*C*H*W
  float* attn = out + NELEM;                  // attn_map: BH * L * L

  float* ws   = (float*)d_ws;
  float* xn   = ws;
  float* q    = xn + NELEM;
  float* k    = q + NELEM;
  float* v    = k + NELEM;
  float* a    = v + NELEM;
  float2* st  = (float2*)(a + NELEM);         // BH*L rows

  // 1. GroupNorm
  gn_kernel<<<B_ * GROUPS_, 256, 0, stream>>>(x, gam, bet, xn);

  // 2. Q/K/V projections
  dim3 gconv(L_ / 64, INNER_ / 64, B_);
  conv1x1_kernel<<<gconv, 256, 0, stream>>>(Wq, bq, xn, nullptr, q, 0);
  conv1x1_kernel<<<gconv, 256, 0, stream>>>(Wk, bk, xn, nullptr, k, 0);
  conv1x1_kernel<<<gconv, 256, 0, stream>>>(Wv, bv, xn, nullptr, v, 0);

  // 3. Scores -> attn_map output (raw logits)
  dim3 gsc(L_ / 64, L_ / 64, BH_);
  scores_kernel<<<gsc, 256, 0, stream>>>(q, k, attn);

  // 4. Softmax row stats
  softmax_stats_kernel<<<(BH_ * L_) / 4, 256, 0, stream>>>(attn, st);

  // 5. PV with on-the-fly softmax
  dim3 gpv(L_ / 64, BH_);
  pv_kernel<<<gpv, 256, 0, stream>>>(attn, st, v, a);

  // 6. Output projection + residual
  conv1x1_kernel<<<gconv, 256, 0, stream>>>(Wo, bo, a, x, out, 1);
}

// Round 2
// 490.145 us; speedup vs baseline: 2.3737x; 2.3737x over previous
//
#include <hip/hip_runtime.h>
#include <math.h>

#define B_      8
#define C_      512
#define L_      1024
#define NH_     8
#define D_      64
#define BH_     64
#define GROUPS_ 32
#define CPG_    16
#define EPS_    1e-5f

typedef __attribute__((ext_vector_type(8))) short bf16x8;   // 8 bf16 = 4 VGPRs
typedef __attribute__((ext_vector_type(4))) float f32x4;

__device__ __forceinline__ unsigned short f2bf(float f) {
  union { float f; unsigned u; } v; v.f = f;
  unsigned r = v.u + 0x7FFFu + ((v.u >> 16) & 1u);   // RNE
  return (unsigned short)(r >> 16);
}

// ---------------------------------------------------------------------------
// GroupNorm -> xn_t[b][l][c] in bf16 (c contiguous). One block per (b,group).
// ---------------------------------------------------------------------------
__global__ void __launch_bounds__(256) gn_kernel(
    const float* __restrict__ x, const float* __restrict__ gamma,
    const float* __restrict__ beta, unsigned short* __restrict__ xn_t) {
  int b = blockIdx.x >> 5, g = blockIdx.x & 31;
  int tid = threadIdx.x;
  const float* xp = x + ((size_t)b * C_ + g * CPG_) * L_;
  float vals[CPG_][4];
  float s = 0.f, ss = 0.f;
#pragma unroll
  for (int c = 0; c < CPG_; ++c)
#pragma unroll
    for (int r = 0; r < 4; ++r) {
      float v = xp[(size_t)c * L_ + tid + r * 256];   // coalesced
      vals[c][r] = v; s += v; ss += v * v;
    }
  __shared__ float red0[256], red1[256];
  red0[tid] = s; red1[tid] = ss;
  __syncthreads();
  for (int off = 128; off > 0; off >>= 1) {
    if (tid < off) { red0[tid] += red0[tid + off]; red1[tid] += red1[tid + off]; }
    __syncthreads();
  }
  float mean = red0[0] * (1.f / 16384.f);
  float var  = red1[0] * (1.f / 16384.f) - mean * mean;
  float rstd = rsqrtf(var + EPS_);
#pragma unroll
  for (int r = 0; r < 4; ++r) {
    int l = tid + r * 256;
    unsigned short obuf[16];
#pragma unroll
    for (int c = 0; c < CPG_; ++c) {
      float gm = gamma[g * CPG_ + c], bt = beta[g * CPG_ + c];  // wave-uniform
      obuf[c] = f2bf((vals[c][r] - mean) * rstd * gm + bt);
    }
    unsigned short* dst = xn_t + ((size_t)b * L_ + l) * C_ + g * CPG_;
    *(bf16x8*)dst       = *(bf16x8*)obuf;
    *(bf16x8*)(dst + 8) = *(bf16x8*)(obuf + 8);
  }
}

// ---------------------------------------------------------------------------
// Cast 4 weight matrices (512x512 fp32) to bf16, layout preserved.
// ---------------------------------------------------------------------------
__global__ void __launch_bounds__(256) cast_w_kernel(
    const float* __restrict__ w0, const float* __restrict__ w1,
    const float* __restrict__ w2, const float* __restrict__ w3,
    unsigned short* __restrict__ o0, unsigned short* __restrict__ o1,
    unsigned short* __restrict__ o2, unsigned short* __restrict__ o3) {
  const float* src; unsigned short* dst;
  switch (blockIdx.y) {
    case 0: src = w0; dst = o0; break;
    case 1: src = w1; dst = o1; break;
    case 2: src = w2; dst = o2; break;
    default: src = w3; dst = o3; break;
  }
  int i = (blockIdx.x * 256 + threadIdx.x) * 4;
  float4 v = *(const float4*)(src + i);
  unsigned short o[4] = {f2bf(v.x), f2bf(v.y), f2bf(v.z), f2bf(v.w)};
  *(unsigned long long*)(dst + i) = *(unsigned long long*)o;
}

// ---------------------------------------------------------------------------
// NT bf16 MFMA GEMM: D[m][n] = sum_k A[m][k]*B[n][k]   (both k-contiguous)
// Tile BM x 128, BK=64, 4 waves. BM=128: wave=64x64 (MI=4); BM=64: 32x64.
// z-batch offsets: off = (z/zdiv)*so + (z%zdiv)*si  (element strides).
// ---------------------------------------------------------------------------
template<int BM, bool BIAS_COL, bool BIAS_ROW, bool OUT_F32, bool RESID, bool SCALE8>
__global__ void __launch_bounds__(256) mfma_gemm(
    const unsigned short* __restrict__ A, const unsigned short* __restrict__ B,
    void* __restrict__ Dv, const float* __restrict__ bias,
    const float* __restrict__ resid, int K, int lda, int ldb, int ldd,
    int zdiv, long sAo, long sAi, long sBo, long sBi, long sDo, long sDi) {
  constexpr int BN = 128, BK = 64, PK = 72;
  constexpr int MI = BM / 32;       // m-frags per wave
  constexpr int WM = BM / 2;        // wave m extent
  __shared__ unsigned short As[BM * PK];
  __shared__ unsigned short Bs[BN * PK];
  int tid = threadIdx.x;
  int wave = tid >> 6, lane = tid & 63;
  int lm = lane & 15, q = lane >> 4;
  int wm = wave >> 1, wn = wave & 1;
  int m0 = blockIdx.x * BM, n0 = blockIdx.y * BN;
  int z = blockIdx.z;
  int zo = z / zdiv, zi = z % zdiv;
  const unsigned short* Ab = A + (size_t)zo * sAo + (size_t)zi * sAi;
  const unsigned short* Bb = B + (size_t)zo * sBo + (size_t)zi * sBi;

  f32x4 acc[MI][4];
#pragma unroll
  for (int mi = 0; mi < MI; ++mi)
#pragma unroll
    for (int ni = 0; ni < 4; ++ni) acc[mi][ni] = (f32x4){0.f, 0.f, 0.f, 0.f};

  int srow = tid >> 3;              // 0..31
  int skp  = (tid & 7) * 8;         // k position (8 bf16 = 16B)

  for (int k0 = 0; k0 < K; k0 += BK) {
#pragma unroll
    for (int p = 0; p < BM / 32; ++p) {
      int r = srow + p * 32;
      *(bf16x8*)&As[r * PK + skp] =
          *(const bf16x8*)&Ab[(size_t)(m0 + r) * lda + k0 + skp];
    }
#pragma unroll
    for (int p = 0; p < 4; ++p) {
      int r = srow + p * 32;
      *(bf16x8*)&Bs[r * PK + skp] =
          *(const bf16x8*)&Bb[(size_t)(n0 + r) * ldb + k0 + skp];
    }
    __syncthreads();
#pragma unroll
    for (int kk = 0; kk < 2; ++kk) {
      bf16x8 af[MI], bfr[4];
#pragma unroll
      for (int mi = 0; mi < MI; ++mi)
        af[mi] = *(const bf16x8*)&As[(wm * WM + mi * 16 + lm) * PK + kk * 32 + q * 8];
#pragma unroll
      for (int ni = 0; ni < 4; ++ni)
        bfr[ni] = *(const bf16x8*)&Bs[(wn * 64 + ni * 16 + lm) * PK + kk * 32 + q * 8];
#pragma unroll
      for (int mi = 0; mi < MI; ++mi)
#pragma unroll
        for (int ni = 0; ni < 4; ++ni)
          acc[mi][ni] = __builtin_amdgcn_mfma_f32_16x16x32_bf16(
              af[mi], bfr[ni], acc[mi][ni], 0, 0, 0);
    }
    __syncthreads();
  }

  float* Df = (float*)Dv + (size_t)zo * sDo + (size_t)zi * sDi;
  unsigned short* Dh = (unsigned short*)Dv + (size_t)zo * sDo + (size_t)zi * sDi;
  const float* Rb = resid ? resid + (size_t)zo * sDo + (size_t)zi * sDi : (const float*)0;
#pragma unroll
  for (int mi = 0; mi < MI; ++mi) {
#pragma unroll
    for (int ni = 0; ni < 4; ++ni) {
      int n = n0 + wn * 64 + ni * 16 + lm;
      float bc = BIAS_COL ? bias[n] : 0.f;
#pragma unroll
      for (int r = 0; r < 4; ++r) {
        int m = m0 + wm * WM + mi * 16 + q * 4 + r;
        float v = acc[mi][ni][r];
        if (SCALE8) v *= 0.125f;
        if (BIAS_COL) v += bc;
        if (BIAS_ROW) v += bias[m];
        size_t idx = (size_t)m * ldd + n;
        if (RESID) v += Rb[idx];
        if (OUT_F32) Df[idx] = v;
        else Dh[idx] = f2bf(v);
      }
    }
  }
}

// ---------------------------------------------------------------------------
// Softmax row stats: per row of attn, max and 1/sum(exp). One wave per row.
// ---------------------------------------------------------------------------
__global__ void __launch_bounds__(256) softmax_stats_kernel(
    const float* __restrict__ S, float2* __restrict__ stats) {
  int row = blockIdx.x * 4 + (threadIdx.x >> 6);
  int lane = threadIdx.x & 63;
  const float* rp = S + (size_t)row * L_;
  float vals[16];
  float m = -INFINITY;
#pragma unroll
  for (int i = 0; i < 16; ++i) {
    vals[i] = rp[lane + i * 64];
    m = fmaxf(m, vals[i]);
  }
#pragma unroll
  for (int off = 32; off > 0; off >>= 1) m = fmaxf(m, __shfl_xor(m, off));
  float s = 0.f;
#pragma unroll
  for (int i = 0; i < 16; ++i) s += expf(vals[i] - m);
#pragma unroll
  for (int off = 32; off > 0; off >>= 1) s += __shfl_xor(s, off);
  if (lane == 0) stats[row] = make_float2(m, 1.0f / s);
}

// ---------------------------------------------------------------------------
// PV: a_t[b][t][h*64+d] = sum_s P[t][s] * v[b][h*64+d][s], P = softmaxed attn
// computed in-flight (fp32 attn -> exp -> bf16 LDS). Tile 128(t) x 64(d).
// ---------------------------------------------------------------------------
__global__ void __launch_bounds__(256) pv_mfma_kernel(
    const float* __restrict__ S, const float2* __restrict__ stats,
    const unsigned short* __restrict__ v, unsigned short* __restrict__ a_t) {
  constexpr int PK = 72;
  __shared__ unsigned short Ps[128 * PK];
  __shared__ unsigned short Vs[64 * PK];
  int tid = threadIdx.x, wave = tid >> 6, lane = tid & 63;
  int lm = lane & 15, q = lane >> 4;
  int t0 = blockIdx.x * 128;
  int bh = blockIdx.y, b = bh >> 3, h = bh & 7;
  const float* Sb = S + (size_t)bh * L_ * L_;
  const float2* stb = stats + (size_t)bh * L_;
  const unsigned short* vb = v + ((size_t)b * C_ + h * 64) * L_;
  unsigned short* ab = a_t + (size_t)b * L_ * C_ + h * 64;

  f32x4 acc[2][4];
#pragma unroll
  for (int mi = 0; mi < 2; ++mi)
#pragma unroll
    for (int ni = 0; ni < 4; ++ni) acc[mi][ni] = (f32x4){0.f, 0.f, 0.f, 0.f};

  int prow = tid >> 4;          // P: 16 rows/pass
  int pc4  = (tid & 15) * 4;    // float4 col
  int vrow = tid >> 3;          // V: 32 rows/pass
  int vkp  = (tid & 7) * 8;

  for (int s0 = 0; s0 < L_; s0 += 64) {
#pragma unroll
    for (int p = 0; p < 2; ++p) {
      int d = vrow + p * 32;
      *(bf16x8*)&Vs[d * PK + vkp] = *(const bf16x8*)&vb[(size_t)d * L_ + s0 + vkp];
    }
#pragma unroll
    for (int p = 0; p < 8; ++p) {
      int t = prow + p * 16;
      float2 st = stb[t0 + t];
      float4 sv = *(const float4*)&Sb[(size_t)(t0 + t) * L_ + s0 + pc4];
      unsigned short e[4];
      e[0] = f2bf(__expf(sv.x - st.x) * st.y);
      e[1] = f2bf(__expf(sv.y - st.x) * st.y);
      e[2] = f2bf(__expf(sv.z - st.x) * st.y);
      e[3] = f2bf(__expf(sv.w - st.x) * st.y);
      *(unsigned long long*)&Ps[t * PK + pc4] = *(unsigned long long*)e;
    }
    __syncthreads();
#pragma unroll
    for (int kk = 0; kk < 2; ++kk) {
      bf16x8 af[2], bfr[4];
#pragma unroll
      for (int mi = 0; mi < 2; ++mi)
        af[mi] = *(const bf16x8*)&Ps[(wave * 32 + mi * 16 + lm) * PK + kk * 32 + q * 8];
#pragma unroll
      for (int ni = 0; ni < 4; ++ni)
        bfr[ni] = *(const bf16x8*)&Vs[(ni * 16 + lm) * PK + kk * 32 + q * 8];
#pragma unroll
      for (int mi = 0; mi < 2; ++mi)
#pragma unroll
        for (int ni = 0; ni < 4; ++ni)
          acc[mi][ni] = __builtin_amdgcn_mfma_f32_16x16x32_bf16(
              af[mi], bfr[ni], acc[mi][ni], 0, 0, 0);
    }
    __syncthreads();
  }
#pragma unroll
  for (int mi = 0; mi < 2; ++mi)
#pragma unroll
    for (int ni = 0; ni < 4; ++ni)
#pragma unroll
      for (int r = 0; r < 4; ++r) {
        int t = t0 + wave * 32 + mi * 16 + q * 4 + r;
        int d = ni * 16 + lm;
        ab[(size_t)t * C_ + d] = f2bf(acc[mi][ni][r]);
      }
}

// ---------------------------------------------------------------------------
extern "C" void kernel_launch(void* const* d_in, const int* in_sizes, int n_in,
                              void* d_out, int out_size, void* d_ws, size_t ws_size,
                              hipStream_t stream) {
  const float* x   = (const float*)d_in[0];
  const float* gam = (const float*)d_in[2];
  const float* bet = (const float*)d_in[3];
  const float* Wq  = (const float*)d_in[4];
  const float* bq  = (const float*)d_in[5];
  const float* Wk  = (const float*)d_in[6];
  const float* bk  = (const float*)d_in[7];
  const float* Wv  = (const float*)d_in[8];
  const float* bv  = (const float*)d_in[9];
  const float* Wo  = (const float*)d_in[10];
  const float* bo  = (const float*)d_in[11];

  const size_t NE = (size_t)B_ * C_ * L_;       // 4194304
  float* out  = (float*)d_out;
  float* attn = out + NE;                       // 64*1024*1024 fp32

  char* ws = (char*)d_ws;
  unsigned short* xn_t = (unsigned short*)(ws);                       // [b][l][c]
  unsigned short* q_t  = (unsigned short*)(ws + 8388608);             // [b][l][o]
  unsigned short* k_t  = (unsigned short*)(ws + 16777216);            // [b][l][o]
  unsigned short* v    = (unsigned short*)(ws + 25165824);            // [b][o][l]
  unsigned short* a_t  = (unsigned short*)(ws + 33554432);            // [b][l][o]
  unsigned short* wqb  = (unsigned short*)(ws + 41943040);
  unsigned short* wkb  = (unsigned short*)(ws + 42467328);
  unsigned short* wvb  = (unsigned short*)(ws + 42991616);
  unsigned short* wob  = (unsigned short*)(ws + 43515904);
  float2*         st   = (float2*)(ws + 44040192);                    // 65536 rows

  const long SBL = (long)C_ * L_;               // 524288 elems per batch

  gn_kernel<<<B_ * GROUPS_, 256, 0, stream>>>(x, gam, bet, xn_t);
  cast_w_kernel<<<dim3(256, 4), 256, 0, stream>>>(Wq, Wk, Wv, Wo, wqb, wkb, wvb, wob);

  // Q, K: D[l][o] = sum_c xn_t[l][c] * W[o][c] + b[o]
  mfma_gemm<64, true, false, false, false, false><<<dim3(16, 4, 8), 256, 0, stream>>>(
      xn_t, wqb, q_t, bq, nullptr, 512, 512, 512, 512, 1, SBL, 0, 0, 0, SBL, 0);
  mfma_gemm<64, true, false, false, false, false><<<dim3(16, 4, 8), 256, 0, stream>>>(
      xn_t, wkb, k_t, bk, nullptr, 512, 512, 512, 512, 1, SBL, 0, 0, 0, SBL, 0);
  // V: D[o][l] = sum_c Wv[o][c] * xn_t[l][c] + b[o]
  mfma_gemm<64, false, true, false, false, false><<<dim3(8, 8, 8), 256, 0, stream>>>(
      wvb, xn_t, v, bv, nullptr, 512, 512, 512, 1024, 1, 0, 0, SBL, 0, SBL, 0);
  // Scores: attn[bh][t][s] = 0.125 * sum_d q_t[t][d] k_t[s][d]  (fp32 out)
  mfma_gemm<128, false, false, true, false, true><<<dim3(8, 8, 64), 256, 0, stream>>>(
      q_t, k_t, attn, nullptr, nullptr, 64, 512, 512, 1024,
      8, SBL, 64, SBL, 64, 8L * 1048576, 1048576);
  softmax_stats_kernel<<<(BH_ * L_) / 4, 256, 0, stream>>>(attn, st);
  pv_mfma_kernel<<<dim3(8, BH_), 256, 0, stream>>>(attn, st, v, a_t);
  // Out: D[o][l] = sum_i Wo[o][i] a_t[l][i] + bo[o] + x  (fp32 out)
  mfma_gemm<64, false, true, true, true, false><<<dim3(8, 8, 8), 256, 0, stream>>>(
      wob, a_t, out, bo, x, 512, 512, 512, 1024, 1, 0, 0, SBL, 0, SBL, 0);
}

// Round 3
// 415.912 us; speedup vs baseline: 2.7974x; 1.1785x over previous
//
#include <hip/hip_runtime.h>
#include <math.h>

#define B_      8
#define C_      512
#define L_      1024
#define NH_     8
#define D_      64
#define BH_     64
#define GROUPS_ 32
#define CPG_    16
#define EPS_    1e-5f

typedef __attribute__((ext_vector_type(8))) short bf16x8;   // 8 bf16 = 4 VGPRs
typedef __attribute__((ext_vector_type(4))) float f32x4;

__device__ __forceinline__ unsigned short f2bf(float f) {
  union { float f; unsigned u; } v; v.f = f;
  unsigned r = v.u + 0x7FFFu + ((v.u >> 16) & 1u);   // RNE
  return (unsigned short)(r >> 16);
}

// ---------------------------------------------------------------------------
// GroupNorm -> xn_t[b][l][c] in bf16 (c contiguous). One block per (b,group).
// ---------------------------------------------------------------------------
__global__ void __launch_bounds__(256) gn_kernel(
    const float* __restrict__ x, const float* __restrict__ gamma,
    const float* __restrict__ beta, unsigned short* __restrict__ xn_t) {
  int b = blockIdx.x >> 5, g = blockIdx.x & 31;
  int tid = threadIdx.x;
  const float* xp = x + ((size_t)b * C_ + g * CPG_) * L_;
  float vals[CPG_][4];
  float s = 0.f, ss = 0.f;
#pragma unroll
  for (int c = 0; c < CPG_; ++c)
#pragma unroll
    for (int r = 0; r < 4; ++r) {
      float v = xp[(size_t)c * L_ + tid + r * 256];   // coalesced
      vals[c][r] = v; s += v; ss += v * v;
    }
  __shared__ float red0[256], red1[256];
  red0[tid] = s; red1[tid] = ss;
  __syncthreads();
  for (int off = 128; off > 0; off >>= 1) {
    if (tid < off) { red0[tid] += red0[tid + off]; red1[tid] += red1[tid + off]; }
    __syncthreads();
  }
  float mean = red0[0] * (1.f / 16384.f);
  float var  = red1[0] * (1.f / 16384.f) - mean * mean;
  float rstd = rsqrtf(var + EPS_);
#pragma unroll
  for (int r = 0; r < 4; ++r) {
    int l = tid + r * 256;
    unsigned short obuf[16];
#pragma unroll
    for (int c = 0; c < CPG_; ++c) {
      float gm = gamma[g * CPG_ + c], bt = beta[g * CPG_ + c];  // wave-uniform
      obuf[c] = f2bf((vals[c][r] - mean) * rstd * gm + bt);
    }
    unsigned short* dst = xn_t + ((size_t)b * L_ + l) * C_ + g * CPG_;
    *(bf16x8*)dst       = *(bf16x8*)obuf;
    *(bf16x8*)(dst + 8) = *(bf16x8*)(obuf + 8);
  }
}

// ---------------------------------------------------------------------------
// Cast 4 weight matrices (512x512 fp32) to bf16. Wq additionally scaled by
// 0.125 (exact pow2) so the scores GEMM directly produces scaled logits.
// ---------------------------------------------------------------------------
__global__ void __launch_bounds__(256) cast_w_kernel(
    const float* __restrict__ w0, const float* __restrict__ w1,
    const float* __restrict__ w2, const float* __restrict__ w3,
    unsigned short* __restrict__ o0, unsigned short* __restrict__ o1,
    unsigned short* __restrict__ o2, unsigned short* __restrict__ o3) {
  const float* src; unsigned short* dst; float sc;
  switch (blockIdx.y) {
    case 0: src = w0; dst = o0; sc = 0.125f; break;
    case 1: src = w1; dst = o1; sc = 1.f; break;
    case 2: src = w2; dst = o2; sc = 1.f; break;
    default: src = w3; dst = o3; sc = 1.f; break;
  }
  int i = (blockIdx.x * 256 + threadIdx.x) * 4;
  float4 v = *(const float4*)(src + i);
  unsigned short o[4] = {f2bf(v.x * sc), f2bf(v.y * sc), f2bf(v.z * sc), f2bf(v.w * sc)};
  *(unsigned long long*)(dst + i) = *(unsigned long long*)o;
}

// ---------------------------------------------------------------------------
// NT bf16 MFMA GEMM: D[m][n] = sum_k A[m][k]*B[n][k]   (both k-contiguous)
// Tile BM x 128, BK=64, 4 waves. DUAL: blockIdx.z/zdiv picks (B,D,bias) set
// 0 or 1 (Q and K share A). zi = z % zdiv is the batch index.
// ---------------------------------------------------------------------------
template<int BM, bool BIAS_COL, bool BIAS_ROW, bool OUT_F32, bool RESID, bool DUAL>
__global__ void __launch_bounds__(256) mfma_gemm(
    const unsigned short* __restrict__ A,
    const unsigned short* __restrict__ B0, const unsigned short* __restrict__ B1,
    void* __restrict__ D0, void* __restrict__ D1,
    const float* __restrict__ bias0, const float* __restrict__ bias1,
    float bs0, float bs1, const float* __restrict__ resid,
    int K, int lda, int ldb, int ldd, int zdiv,
    long sAi, long sBi, long sDi) {
  constexpr int BN = 128, BK = 64, PK = 72;
  constexpr int MI = BM / 32;
  constexpr int WM = BM / 2;
  __shared__ unsigned short As[BM * PK];
  __shared__ unsigned short Bs[BN * PK];
  int tid = threadIdx.x;
  int wave = tid >> 6, lane = tid & 63;
  int lm = lane & 15, q = lane >> 4;
  int wm = wave >> 1, wn = wave & 1;
  int m0 = blockIdx.x * BM, n0 = blockIdx.y * BN;
  int z = blockIdx.z, zo = z / zdiv, zi = z % zdiv;

  const unsigned short* Ab = A + (size_t)zi * sAi;
  const unsigned short* Bb = ((DUAL && zo) ? B1 : B0) + (size_t)zi * sBi;
  void* Dv = (DUAL && zo) ? D1 : D0;
  const float* bias = (DUAL && zo) ? bias1 : bias0;
  float bscale = (DUAL && zo) ? bs1 : bs0;

  f32x4 acc[MI][4];
#pragma unroll
  for (int mi = 0; mi < MI; ++mi)
#pragma unroll
    for (int ni = 0; ni < 4; ++ni) acc[mi][ni] = (f32x4){0.f, 0.f, 0.f, 0.f};

  int srow = tid >> 3;
  int skp  = (tid & 7) * 8;

  for (int k0 = 0; k0 < K; k0 += BK) {
#pragma unroll
    for (int p = 0; p < BM / 32; ++p) {
      int r = srow + p * 32;
      *(bf16x8*)&As[r * PK + skp] =
          *(const bf16x8*)&Ab[(size_t)(m0 + r) * lda + k0 + skp];
    }
#pragma unroll
    for (int p = 0; p < 4; ++p) {
      int r = srow + p * 32;
      *(bf16x8*)&Bs[r * PK + skp] =
          *(const bf16x8*)&Bb[(size_t)(n0 + r) * ldb + k0 + skp];
    }
    __syncthreads();
#pragma unroll
    for (int kk = 0; kk < 2; ++kk) {
      bf16x8 af[MI], bfr[4];
#pragma unroll
      for (int mi = 0; mi < MI; ++mi)
        af[mi] = *(const bf16x8*)&As[(wm * WM + mi * 16 + lm) * PK + kk * 32 + q * 8];
#pragma unroll
      for (int ni = 0; ni < 4; ++ni)
        bfr[ni] = *(const bf16x8*)&Bs[(wn * 64 + ni * 16 + lm) * PK + kk * 32 + q * 8];
#pragma unroll
      for (int mi = 0; mi < MI; ++mi)
#pragma unroll
        for (int ni = 0; ni < 4; ++ni)
          acc[mi][ni] = __builtin_amdgcn_mfma_f32_16x16x32_bf16(
              af[mi], bfr[ni], acc[mi][ni], 0, 0, 0);
    }
    __syncthreads();
  }

  float* Df = (float*)Dv + (size_t)zi * sDi;
  unsigned short* Dh = (unsigned short*)Dv + (size_t)zi * sDi;
  const float* Rb = RESID ? resid + (size_t)zi * sDi : (const float*)0;
#pragma unroll
  for (int mi = 0; mi < MI; ++mi) {
#pragma unroll
    for (int ni = 0; ni < 4; ++ni) {
      int n = n0 + wn * 64 + ni * 16 + lm;
      float bc = BIAS_COL ? bias[n] * bscale : 0.f;
#pragma unroll
      for (int r = 0; r < 4; ++r) {
        int m = m0 + wm * WM + mi * 16 + q * 4 + r;
        float v = acc[mi][ni][r];
        if (BIAS_COL) v += bc;
        if (BIAS_ROW) v += bias[m] * bscale;
        size_t idx = (size_t)m * ldd + n;
        if (RESID) v += Rb[idx];
        if (OUT_F32) Df[idx] = v;
        else Dh[idx] = f2bf(v);
      }
    }
  }
}

// ---------------------------------------------------------------------------
// Fused flash attention: per (bh, 128 t-rows): loop s-tiles of 64:
//   S = Q.K^T (MFMA, Q in regs) -> write raw logits to attn (output) ->
//   online softmax (m,l in regs, per-lane alpha rescale of O) ->
//   P -> per-wave LDS (C-layout -> A-layout) -> O += P.V (MFMA).
// Layouts: q_t/k_t [b][l][h*64+d] (d contig), v [b][h*64+d][s] (s contig),
// a_t out [b][t][h*64+d].
// ---------------------------------------------------------------------------
#define PKF 72
#define PPF 80
__global__ void __launch_bounds__(256) flash_kernel(
    const unsigned short* __restrict__ q_t, const unsigned short* __restrict__ k_t,
    const unsigned short* __restrict__ v, float* __restrict__ attn,
    unsigned short* __restrict__ a_t) {
  __shared__ unsigned short Ks[64 * PKF];
  __shared__ unsigned short Vs[64 * PKF];
  __shared__ unsigned short Ps[4 * 32 * PPF];
  int tid = threadIdx.x, wave = tid >> 6, lane = tid & 63;
  int lm = lane & 15, q = lane >> 4;
  int t0 = blockIdx.x * 128, bh = blockIdx.y, b = bh >> 3, h = bh & 7;
  int tw = t0 + wave * 32;
  const unsigned short* qb = q_t + (size_t)b * L_ * C_ + h * 64;
  const unsigned short* kb = k_t + (size_t)b * L_ * C_ + h * 64;
  const unsigned short* vb = v + ((size_t)b * C_ + h * 64) * L_;
  float* Sb = attn + (size_t)bh * L_ * L_;
  unsigned short* ab = a_t + (size_t)b * L_ * C_ + h * 64;
  unsigned short* Pw = Ps + wave * 32 * PPF;

  // Q fragments, resident all kernel (Wq pre-scaled by 0.125)
  bf16x8 aq[2][2];
#pragma unroll
  for (int mi = 0; mi < 2; ++mi)
#pragma unroll
    for (int kk = 0; kk < 2; ++kk)
      aq[mi][kk] = *(const bf16x8*)&qb[(size_t)(tw + mi * 16 + lm) * C_ + kk * 32 + q * 8];

  f32x4 acc_o[2][4];
  float m_i[2][4], l_i[2][4];
#pragma unroll
  for (int mi = 0; mi < 2; ++mi)
#pragma unroll
    for (int r = 0; r < 4; ++r) { m_i[mi][r] = -1e30f; l_i[mi][r] = 0.f; }
#pragma unroll
  for (int mi = 0; mi < 2; ++mi)
#pragma unroll
    for (int ni = 0; ni < 4; ++ni) acc_o[mi][ni] = (f32x4){0.f, 0.f, 0.f, 0.f};

  int srow = tid >> 2, scol = (tid & 3) * 16;

  for (int s0 = 0; s0 < L_; s0 += 64) {
    __syncthreads();   // all waves done reading Ks/Vs from previous step
    *(bf16x8*)&Ks[srow * PKF + scol]     = *(const bf16x8*)&kb[(size_t)(s0 + srow) * C_ + scol];
    *(bf16x8*)&Ks[srow * PKF + scol + 8] = *(const bf16x8*)&kb[(size_t)(s0 + srow) * C_ + scol + 8];
    *(bf16x8*)&Vs[srow * PKF + scol]     = *(const bf16x8*)&vb[(size_t)srow * L_ + s0 + scol];
    *(bf16x8*)&Vs[srow * PKF + scol + 8] = *(const bf16x8*)&vb[(size_t)srow * L_ + s0 + scol + 8];
    __syncthreads();

    // S = Q.K^T
    f32x4 acc_s[2][4];
#pragma unroll
    for (int mi = 0; mi < 2; ++mi)
#pragma unroll
      for (int ni = 0; ni < 4; ++ni) acc_s[mi][ni] = (f32x4){0.f, 0.f, 0.f, 0.f};
#pragma unroll
    for (int kk = 0; kk < 2; ++kk) {
      bf16x8 bk[4];
#pragma unroll
      for (int ni = 0; ni < 4; ++ni)
        bk[ni] = *(const bf16x8*)&Ks[(ni * 16 + lm) * PKF + kk * 32 + q * 8];
#pragma unroll
      for (int mi = 0; mi < 2; ++mi)
#pragma unroll
        for (int ni = 0; ni < 4; ++ni)
          acc_s[mi][ni] = __builtin_amdgcn_mfma_f32_16x16x32_bf16(
              aq[mi][kk], bk[ni], acc_s[mi][ni], 0, 0, 0);
    }

    // online softmax + raw-logit store + P to LDS
#pragma unroll
    for (int mi = 0; mi < 2; ++mi) {
#pragma unroll
      for (int r = 0; r < 4; ++r) {
        float rm = fmaxf(fmaxf(acc_s[mi][0][r], acc_s[mi][1][r]),
                         fmaxf(acc_s[mi][2][r], acc_s[mi][3][r]));
        rm = fmaxf(rm, __shfl_xor(rm, 1));
        rm = fmaxf(rm, __shfl_xor(rm, 2));
        rm = fmaxf(rm, __shfl_xor(rm, 4));
        rm = fmaxf(rm, __shfl_xor(rm, 8));
        float mo = m_i[mi][r];
        float mn = fmaxf(mo, rm);
        float al = __expf(mo - mn);
        m_i[mi][r] = mn;
        int t = tw + mi * 16 + q * 4 + r;
        float ps = 0.f;
#pragma unroll
        for (int ni = 0; ni < 4; ++ni) {
          float sv = acc_s[mi][ni][r];
          Sb[(size_t)t * L_ + s0 + ni * 16 + lm] = sv;   // raw logit out
          float p = __expf(sv - mn);
          ps += p;
          acc_s[mi][ni][r] = p;
        }
        l_i[mi][r] = l_i[mi][r] * al + ps;
#pragma unroll
        for (int ni = 0; ni < 4; ++ni) acc_o[mi][ni][r] *= al;
#pragma unroll
        for (int ni = 0; ni < 4; ++ni)
          Pw[(mi * 16 + q * 4 + r) * PPF + ni * 16 + lm] = f2bf(acc_s[mi][ni][r]);
      }
    }

    // O += P.V  (Pw is wave-private: lgkmcnt ordering suffices, no barrier)
#pragma unroll
    for (int kk = 0; kk < 2; ++kk) {
      bf16x8 ap[2], bv4[4];
#pragma unroll
      for (int mi = 0; mi < 2; ++mi)
        ap[mi] = *(const bf16x8*)&Pw[(mi * 16 + lm) * PPF + kk * 32 + q * 8];
#pragma unroll
      for (int ni = 0; ni < 4; ++ni)
        bv4[ni] = *(const bf16x8*)&Vs[(ni * 16 + lm) * PKF + kk * 32 + q * 8];
#pragma unroll
      for (int mi = 0; mi < 2; ++mi)
#pragma unroll
        for (int ni = 0; ni < 4; ++ni)
          acc_o[mi][ni] = __builtin_amdgcn_mfma_f32_16x16x32_bf16(
              ap[mi], bv4[ni], acc_o[mi][ni], 0, 0, 0);
    }
  }

  // epilogue: finish l reduction, normalize, write a_t
#pragma unroll
  for (int mi = 0; mi < 2; ++mi) {
#pragma unroll
    for (int r = 0; r < 4; ++r) {
      float lf = l_i[mi][r];
      lf += __shfl_xor(lf, 1);
      lf += __shfl_xor(lf, 2);
      lf += __shfl_xor(lf, 4);
      lf += __shfl_xor(lf, 8);
      float rinv = 1.0f / lf;
      int t = tw + mi * 16 + q * 4 + r;
#pragma unroll
      for (int ni = 0; ni < 4; ++ni)
        ab[(size_t)t * C_ + ni * 16 + lm] = f2bf(acc_o[mi][ni][r] * rinv);
    }
  }
}

// ---------------------------------------------------------------------------
extern "C" void kernel_launch(void* const* d_in, const int* in_sizes, int n_in,
                              void* d_out, int out_size, void* d_ws, size_t ws_size,
                              hipStream_t stream) {
  const float* x   = (const float*)d_in[0];
  const float* gam = (const float*)d_in[2];
  const float* bet = (const float*)d_in[3];
  const float* Wq  = (const float*)d_in[4];
  const float* bq  = (const float*)d_in[5];
  const float* Wk  = (const float*)d_in[6];
  const float* bk  = (const float*)d_in[7];
  const float* Wv  = (const float*)d_in[8];
  const float* bv  = (const float*)d_in[9];
  const float* Wo  = (const float*)d_in[10];
  const float* bo  = (const float*)d_in[11];

  const size_t NE = (size_t)B_ * C_ * L_;
  float* out  = (float*)d_out;
  float* attn = out + NE;

  char* ws = (char*)d_ws;
  unsigned short* xn_t = (unsigned short*)(ws);             // [b][l][c]
  unsigned short* q_t  = (unsigned short*)(ws + 8388608);   // [b][l][o]
  unsigned short* k_t  = (unsigned short*)(ws + 16777216);  // [b][l][o]
  unsigned short* v    = (unsigned short*)(ws + 25165824);  // [b][o][l]
  unsigned short* a_t  = (unsigned short*)(ws + 33554432);  // [b][l][o]
  unsigned short* wqb  = (unsigned short*)(ws + 41943040);
  unsigned short* wkb  = (unsigned short*)(ws + 42467328);
  unsigned short* wvb  = (unsigned short*)(ws + 42991616);
  unsigned short* wob  = (unsigned short*)(ws + 43515904);

  const long SBL = (long)C_ * L_;   // 524288 elems per batch

  gn_kernel<<<B_ * GROUPS_, 256, 0, stream>>>(x, gam, bet, xn_t);
  cast_w_kernel<<<dim3(256, 4), 256, 0, stream>>>(Wq, Wk, Wv, Wo, wqb, wkb, wvb, wob);

  // Q and K in one dual dispatch: D[l][o] = sum_c xn[l][c]*W[o][c] + b[o]
  mfma_gemm<64, true, false, false, false, true><<<dim3(16, 4, 16), 256, 0, stream>>>(
      xn_t, wqb, wkb, q_t, k_t, bq, bk, 0.125f, 1.f, nullptr,
      512, 512, 512, 512, 8, SBL, 0, SBL);
  // V: D[o][l] = sum_c Wv[o][c]*xn[l][c] + b[o]
  mfma_gemm<64, false, true, false, false, false><<<dim3(8, 8, 8), 256, 0, stream>>>(
      wvb, xn_t, nullptr, v, nullptr, bv, nullptr, 1.f, 1.f, nullptr,
      512, 512, 512, 1024, 8, 0, SBL, SBL);

  // Fused scores + softmax + PV
  flash_kernel<<<dim3(8, BH_), 256, 0, stream>>>(q_t, k_t, v, attn, a_t);

  // Out: D[o][l] = sum_i Wo[o][i]*a_t[l][i] + bo[o] + x
  mfma_gemm<64, false, true, true, true, false><<<dim3(8, 8, 8), 256, 0, stream>>>(
      wob, a_t, nullptr, out, nullptr, bo, nullptr, 1.f, 1.f, x,
      512, 512, 512, 1024, 8, 0, SBL, SBL);
}